// Round 1
// baseline (1917.895 us; speedup 1.0000x reference)
//
#include <hip/hip_runtime.h>

#define NT    8192
#define NP    8200
#define NB    64
#define DV    64
#define NMODE 64
#define NL    4
#define KSPL  8
#define KCH   1025   // NP / KSPL

// ---------------- workspace layout (floats) ----------------
static const size_t OFF_X    = 0;                                  // x: [NB][DV][NP]
static const size_t OFF_TABF = OFF_X    + (size_t)NB*DV*NP;        // tabF: [NP][128]  (cos,sin interleaved)
static const size_t OFF_TABI = OFF_TABF + (size_t)NP*2*NMODE;      // tabI: [128][NP]
static const size_t OFF_XP   = OFF_TABI + (size_t)NP*2*NMODE;      // xpart: [KSPL][NB][DV][128]
static const size_t OFF_Z    = OFF_XP   + (size_t)KSPL*NB*DV*2*NMODE; // Z: [NB][DV][128]

// ---------------- trig tables ----------------
__global__ void k_tab(float* __restrict__ tabF, float* __restrict__ tabI) {
    int idx = blockIdx.x * 256 + threadIdx.x;
    if (idx >= NP * NMODE) return;
    int t = idx >> 6;
    int k = idx & 63;
    int m = (int)(((long long)t * (long long)k) % NP);
    float th = (float)m * (float)(6.283185307179586476925286766559 / (double)NP);
    float s, c;
    sincosf(th, &s, &c);
    tabF[(size_t)t * 128 + 2 * k]     = c;
    tabF[(size_t)t * 128 + 2 * k + 1] = s;
    tabI[(size_t)(2 * k) * NP + t]     = c;
    tabI[(size_t)(2 * k + 1) * NP + t] = s;
}

// ---------------- initial projection: x[b][c][t] ----------------
__global__ void k_proj(const float* __restrict__ v, const float* __restrict__ grd,
                       const float* __restrict__ pw, const float* __restrict__ pb,
                       float* __restrict__ x) {
    int b = blockIdx.y;
    int t = blockIdx.x * 256 + threadIdx.x;
    if (t >= NP) return;
    float vv = 0.f, gg = 0.f;
    bool in = (t < NT);
    if (in) { vv = v[(size_t)b * NT + t]; gg = grd[t]; }
    #pragma unroll 8
    for (int c = 0; c < DV; ++c) {
        float val = in ? fmaf(vv, pw[c], fmaf(gg, pw[DV + c], pb[c])) : 0.f;
        x[((size_t)b * DV + c) * NP + t] = val;
    }
}

// ---------------- forward DFT (k-split partial GEMM) ----------------
// grid (KSPL, NB); C[64 rows=channels][128 cols=2*modes] over t-chunk
__launch_bounds__(256)
__global__ void k_fdft(const float* __restrict__ x, const float* __restrict__ tabF,
                       float* __restrict__ xpart) {
    __shared__ float As[DV][33];
    __shared__ __align__(16) float Bs[32][132];
    int b  = blockIdx.y;
    int ks = blockIdx.x;
    int t0 = ks * KCH;
    int te = t0 + KCH;
    int tid = threadIdx.x;
    int rg = tid >> 5;   // 0..7  -> rows rg*8..rg*8+7
    int cg = tid & 31;   // 0..31 -> cols cg*4..cg*4+3
    float acc[8][4];
    #pragma unroll
    for (int i = 0; i < 8; ++i)
        #pragma unroll
        for (int j = 0; j < 4; ++j) acc[i][j] = 0.f;

    for (int c0 = t0; c0 < te; c0 += 32) {
        // stage A: 64 rows x 32 t
        #pragma unroll
        for (int q = 0; q < 8; ++q) {
            int flat = q * 256 + tid;
            int row = flat >> 5, col = flat & 31;
            int t = c0 + col;
            As[row][col] = (t < te) ? x[((size_t)b * DV + row) * NP + t] : 0.f;
        }
        // stage B: 32 t x 128 (float4)
        #pragma unroll
        for (int q = 0; q < 4; ++q) {
            int flat = q * 256 + tid;
            int tt = flat >> 5, m4 = flat & 31;
            int t = c0 + tt;
            float4 val = make_float4(0.f, 0.f, 0.f, 0.f);
            if (t < te) val = *(const float4*)&tabF[(size_t)t * 128 + m4 * 4];
            *(float4*)&Bs[tt][m4 * 4] = val;
        }
        __syncthreads();
        #pragma unroll
        for (int kk = 0; kk < 32; ++kk) {
            float a[8];
            #pragma unroll
            for (int i = 0; i < 8; ++i) a[i] = As[rg * 8 + i][kk];
            float4 bv = *(const float4*)&Bs[kk][cg * 4];
            #pragma unroll
            for (int i = 0; i < 8; ++i) {
                acc[i][0] = fmaf(a[i], bv.x, acc[i][0]);
                acc[i][1] = fmaf(a[i], bv.y, acc[i][1]);
                acc[i][2] = fmaf(a[i], bv.z, acc[i][2]);
                acc[i][3] = fmaf(a[i], bv.w, acc[i][3]);
            }
        }
        __syncthreads();
    }
    #pragma unroll
    for (int i = 0; i < 8; ++i) {
        float4 st = make_float4(acc[i][0], acc[i][1], acc[i][2], acc[i][3]);
        *(float4*)&xpart[(((size_t)ks * NB + b) * DV + (rg * 8 + i)) * 128 + cg * 4] = st;
    }
}

// ---------------- reduce partials + spectral mix -> Z ----------------
// grid (4, NB): modes kq*16 .. kq*16+15
__launch_bounds__(256)
__global__ void k_spec(const float* __restrict__ xpart, const float* __restrict__ fw_l,
                       float* __restrict__ z) {
    __shared__ float Xs[DV][32];   // [i][2*klocal + comp]  (comp0=sum cos, comp1=sum sin)
    int b = blockIdx.y, kq = blockIdx.x, tid = threadIdx.x;
    #pragma unroll
    for (int q = 0; q < 8; ++q) {
        int flat = q * 256 + tid;              // 2048 values
        int i = flat >> 5, m = flat & 31;
        float s = 0.f;
        #pragma unroll
        for (int ks = 0; ks < KSPL; ++ks)
            s += xpart[(((size_t)ks * NB + b) * DV + i) * 128 + kq * 32 + m];
        Xs[i][m] = s;
    }
    __syncthreads();
    #pragma unroll
    for (int q = 0; q < 4; ++q) {
        int flat = q * 256 + tid;              // 1024 = 64 o x 16 k
        int o = flat >> 4, kl = flat & 15;
        int k = kq * 16 + kl;
        float yr = 0.f, yi = 0.f;
        #pragma unroll 8
        for (int i = 0; i < DV; ++i) {
            float2 xv = *(const float2*)&Xs[i][2 * kl];   // (Xr, Xs_sin); true Xi = -Xs_sin
            float2 w  = *(const float2*)&fw_l[(((size_t)i * DV + o) * NMODE + k) * 2];
            yr = fmaf(xv.x, w.x, fmaf(xv.y, w.y, yr));    // Xr*Wr + Xs*Wi
            yi = fmaf(xv.x, w.y, fmaf(-xv.y, w.x, yi));   // Xr*Wi - Xs*Wr
        }
        float al = (k == 0) ? (1.0f / NP) : (2.0f / NP);
        z[((size_t)b * DV + o) * 128 + 2 * k]     = al * yr;
        z[((size_t)b * DV + o) * 128 + 2 * k + 1] = -al * yi;
    }
}

// ---------------- inverse DFT + local linear + bias + act (in-place x) ----------------
// grid (65, NB); K = 192 = 128 (modes) + 64 (channels); tile: 64 o x 128 t
template <bool RELU, bool LAST>
__launch_bounds__(256)
__global__ void k_inv(const float* __restrict__ z, const float* __restrict__ tabI,
                      const float* __restrict__ ww_l, const float* __restrict__ wb_l,
                      const float* __restrict__ qw, const float* __restrict__ qb,
                      float* __restrict__ x, float* __restrict__ out) {
    __shared__ float ZA[DV][33];
    __shared__ __align__(16) float U[32][132];
    __shared__ float RED[16][128];
    int b = blockIdx.y;
    int t0 = blockIdx.x * 128;
    int tid = threadIdx.x;
    int og = tid >> 4;   // 0..15 -> o = og*4 + i
    int tg = tid & 15;   // 0..15 -> t = t0 + tg*8 + j
    float acc[4][8];
    #pragma unroll
    for (int i = 0; i < 4; ++i)
        #pragma unroll
        for (int j = 0; j < 8; ++j) acc[i][j] = 0.f;

    for (int mc = 0; mc < 6; ++mc) {
        // stage ZA[o][kk]
        if (mc < 4) {
            #pragma unroll
            for (int q = 0; q < 8; ++q) {
                int flat = q * 256 + tid;
                int o = flat >> 5, c = flat & 31;
                ZA[o][c] = z[((size_t)b * DV + o) * 128 + mc * 32 + c];
            }
        } else {
            int i0 = (mc - 4) * 32;
            #pragma unroll
            for (int q = 0; q < 8; ++q) {
                int flat = q * 256 + tid;
                int o = flat & 63, ii = flat >> 6;   // ii 0..3 per q -> 0..31
                ZA[o][ii] = ww_l[(size_t)(i0 + ii) * DV + o];
            }
        }
        // stage U[kk][t]
        #pragma unroll
        for (int q = 0; q < 4; ++q) {
            int flat = q * 256 + tid;
            int c = flat >> 5, t4 = flat & 31;
            float4 val = make_float4(0.f, 0.f, 0.f, 0.f);
            int t = t0 + t4 * 4;
            if (t < NP) {
                if (mc < 4) val = *(const float4*)&tabI[(size_t)(mc * 32 + c) * NP + t];
                else        val = *(const float4*)&x[((size_t)b * DV + ((mc - 4) * 32 + c)) * NP + t];
            }
            *(float4*)&U[c][t4 * 4] = val;
        }
        __syncthreads();
        #pragma unroll
        for (int kk = 0; kk < 32; ++kk) {
            float a[4];
            #pragma unroll
            for (int i = 0; i < 4; ++i) a[i] = ZA[og * 4 + i][kk];
            float4 u0 = *(const float4*)&U[kk][tg * 8];
            float4 u1 = *(const float4*)&U[kk][tg * 8 + 4];
            #pragma unroll
            for (int i = 0; i < 4; ++i) {
                acc[i][0] = fmaf(a[i], u0.x, acc[i][0]);
                acc[i][1] = fmaf(a[i], u0.y, acc[i][1]);
                acc[i][2] = fmaf(a[i], u0.z, acc[i][2]);
                acc[i][3] = fmaf(a[i], u0.w, acc[i][3]);
                acc[i][4] = fmaf(a[i], u1.x, acc[i][4]);
                acc[i][5] = fmaf(a[i], u1.y, acc[i][5]);
                acc[i][6] = fmaf(a[i], u1.z, acc[i][6]);
                acc[i][7] = fmaf(a[i], u1.w, acc[i][7]);
            }
        }
        __syncthreads();
    }

    if (!LAST) {
        #pragma unroll
        for (int i = 0; i < 4; ++i) {
            int o = og * 4 + i;
            float bias = wb_l[o];
            #pragma unroll
            for (int j = 0; j < 8; ++j) {
                int t = t0 + tg * 8 + j;
                if (t < NP) {
                    float vv = acc[i][j] + bias;
                    if (RELU) vv = fmaxf(vv, 0.f);
                    x[((size_t)b * DV + o) * NP + t] = vv;
                }
            }
        }
    } else {
        float part[8];
        #pragma unroll
        for (int j = 0; j < 8; ++j) part[j] = 0.f;
        #pragma unroll
        for (int i = 0; i < 4; ++i) {
            int o = og * 4 + i;
            float bias = wb_l[o];
            float qq = qw[o];
            #pragma unroll
            for (int j = 0; j < 8; ++j) part[j] = fmaf(acc[i][j] + bias, qq, part[j]);
        }
        #pragma unroll
        for (int j = 0; j < 8; ++j) RED[og][tg * 8 + j] = part[j];
        __syncthreads();
        if (tid < 128) {
            float s = 0.f;
            #pragma unroll
            for (int g = 0; g < 16; ++g) s += RED[g][tid];
            int t = t0 + tid;
            if (t < NT) out[(size_t)b * NT + t] = s + qb[0];
        }
    }
}

extern "C" void kernel_launch(void* const* d_in, const int* in_sizes, int n_in,
                              void* d_out, int out_size, void* d_ws, size_t ws_size,
                              hipStream_t stream) {
    const float* v   = (const float*)d_in[0];
    const float* grd = (const float*)d_in[1];
    const float* pw  = (const float*)d_in[2];
    const float* pb  = (const float*)d_in[3];
    const float* fw  = (const float*)d_in[4];
    const float* ww  = (const float*)d_in[5];
    const float* wb  = (const float*)d_in[6];
    const float* qw  = (const float*)d_in[7];
    const float* qb  = (const float*)d_in[8];
    float* out = (float*)d_out;

    float* ws    = (float*)d_ws;
    float* x     = ws + OFF_X;
    float* tabF  = ws + OFF_TABF;
    float* tabI  = ws + OFF_TABI;
    float* xpart = ws + OFF_XP;
    float* zbuf  = ws + OFF_Z;

    k_tab<<<(NP * NMODE + 255) / 256, 256, 0, stream>>>(tabF, tabI);
    k_proj<<<dim3((NP + 255) / 256, NB), 256, 0, stream>>>(v, grd, pw, pb, x);

    for (int l = 0; l < NL; ++l) {
        k_fdft<<<dim3(KSPL, NB), 256, 0, stream>>>(x, tabF, xpart);
        k_spec<<<dim3(4, NB), 256, 0, stream>>>(xpart, fw + (size_t)l * DV * DV * NMODE * 2, zbuf);
        if (l < NL - 1) {
            k_inv<true, false><<<dim3((NP + 127) / 128, NB), 256, 0, stream>>>(
                zbuf, tabI, ww + (size_t)l * DV * DV, wb + (size_t)l * DV, qw, qb, x, out);
        } else {
            k_inv<false, true><<<dim3((NP + 127) / 128, NB), 256, 0, stream>>>(
                zbuf, tabI, ww + (size_t)l * DV * DV, wb + (size_t)l * DV, qw, qb, x, out);
        }
    }
}

// Round 2
// 544.941 us; speedup vs baseline: 3.5195x; 3.5195x over previous
//
#include <hip/hip_runtime.h>

#define NT    8192
#define NP    8200
#define NPP   8320          // padded length: 65*128 = 260*32 = 520*16
#define NB    64
#define DV    64
#define NMODE 64
#define NL    4
#define KSPL  13            // k-split for forward DFT
#define SPB   20            // K-steps (of 32) per fdft block: 13*20 = 260
#define NSTEP 260
#define TFRAGS 520

typedef __bf16 bf16x8 __attribute__((ext_vector_type(8)));
typedef float  f32x4  __attribute__((ext_vector_type(4)));

// ---------------- workspace layout (bytes) ----------------
// x_hi  : [NB][DV][NPP] bf16                     68,157,440
// x_lo  : same                                   68,157,440
// tabFb : [260 step][8 cf][64 lane][8] bf16       2,129,920
// tabIb : [4 ks][520 tf][64 lane][8] bf16         2,129,920
// Wfrag : [NL][2 slab][2 ks][4 mf][64][8] bf16    1,048,576
// zfrag : [NB][4 ks][4 mf][64][8] bf16            1,048,576
// xpart : [KSPL][NB][DV][128] bf16               13,631,488
static const size_t B_XHI   = 0;
static const size_t B_XLO   = B_XHI  + 68157440ull;
static const size_t B_TABF  = B_XLO  + 68157440ull;
static const size_t B_TABI  = B_TABF + 2129920ull;
static const size_t B_WFR   = B_TABI + 2129920ull;
static const size_t B_ZFR   = B_WFR  + 1048576ull;
static const size_t B_XPART = B_ZFR  + 1048576ull;

// ---------------- prep: trig tables in fragment order ----------------
__global__ void k_prep(__bf16* __restrict__ tabFb, __bf16* __restrict__ tabIb) {
    int idx = blockIdx.x * 256 + threadIdx.x;        // (t, k)
    if (idx >= NPP * 64) return;
    int t = idx >> 6, k = idx & 63;
    float c = 0.f, s = 0.f;
    if (t < NP) {
        int m = (int)(((long long)t * (long long)k) % NP);
        float th = (float)m * (float)(6.283185307179586 / (double)NP);
        sincosf(th, &s, &c);
    }
    // tabFb: B[k-dim = t][col = m], frag: step=t>>5, cf=m>>4, lane=(m&15)+16*((t>>3)&3), j=t&7
    {
        int gs = t >> 5, lh = (t >> 3) & 3, j = t & 7;
        int cf = k >> 3;
        int m0 = 2 * k, m1 = 2 * k + 1;
        tabFb[(((size_t)gs * 8 + cf) * 64 + (m0 & 15) + 16 * lh) * 8 + j] = (__bf16)c;
        tabFb[(((size_t)gs * 8 + cf) * 64 + (m1 & 15) + 16 * lh) * 8 + j] = (__bf16)s;
    }
    // tabIb: B[k-dim = m][col = t], frag: ks=m>>5, tf=t>>4, lane=(t&15)+16*((m>>3)&3), j=m&7
    {
        int tf = t >> 4, lt = t & 15;
        int m0 = 2 * k;
        tabIb[(((size_t)(m0 >> 5) * TFRAGS + tf) * 64 + lt + 16 * ((m0 >> 3) & 3)) * 8 + (m0 & 7)] = (__bf16)c;
        int m1 = 2 * k + 1;
        tabIb[(((size_t)(m1 >> 5) * TFRAGS + tf) * 64 + lt + 16 * ((m1 >> 3) & 3)) * 8 + (m1 & 7)] = (__bf16)s;
    }
}

// ---------------- prep: w_w hi/lo in A-fragment order ----------------
__global__ void k_prep_w(const float* __restrict__ ww, __bf16* __restrict__ Wfrag) {
    int idx = blockIdx.x * 256 + threadIdx.x;
    if (idx >= NL * DV * DV) return;
    int l = idx >> 12, cd = idx & 4095, c = cd >> 6, d = cd & 63;
    float wv = ww[((size_t)l * DV + c) * DV + d];     // A[row=d][k=c] = w_w[c,d]
    __bf16 h = (__bf16)wv;
    __bf16 lo = (__bf16)(wv - (float)h);
    int ks = c >> 5, mf = d >> 4;
    int lane = (d & 15) + 16 * ((c >> 3) & 3), j = c & 7;
    Wfrag[((((size_t)l * 2 + 0) * 2 + ks) * 4 + mf) * 64 * 8 + (size_t)lane * 8 + j] = h;
    Wfrag[((((size_t)l * 2 + 1) * 2 + ks) * 4 + mf) * 64 * 8 + (size_t)lane * 8 + j] = lo;
}

// ---------------- initial projection -> x_hi/x_lo ----------------
__global__ void k_proj(const float* __restrict__ v, const float* __restrict__ grd,
                       const float* __restrict__ pw, const float* __restrict__ pb,
                       __bf16* __restrict__ xhi, __bf16* __restrict__ xlo) {
    int b = blockIdx.y;
    int t = blockIdx.x * 256 + threadIdx.x;
    if (t >= NPP) return;
    bool in = (t < NT);
    float vv = in ? v[(size_t)b * NT + t] : 0.f;
    float gg = in ? grd[t] : 0.f;
    #pragma unroll 8
    for (int c = 0; c < DV; ++c) {
        float val = in ? fmaf(vv, pw[c], fmaf(gg, pw[DV + c], pb[c])) : 0.f;
        __bf16 h = (__bf16)val;
        xhi[((size_t)b * DV + c) * NPP + t] = h;
        xlo[((size_t)b * DV + c) * NPP + t] = (__bf16)(val - (float)h);
    }
}

// ---------------- forward DFT: MFMA, no LDS ----------------
// grid (KSPL, NB). Per block: C[64 c][128 m] partial over its t-chunk.
__launch_bounds__(256)
__global__ void k_fdft(const __bf16* __restrict__ xhi, const __bf16* __restrict__ tabFb,
                       __bf16* __restrict__ xpart) {
    int b = blockIdx.y, ksb = blockIdx.x;
    int tid = threadIdx.x, w = tid >> 6, lane = tid & 63;
    int g = lane >> 4, r = lane & 15;
    f32x4 acc[4][2];
    #pragma unroll
    for (int mf = 0; mf < 4; ++mf)
        #pragma unroll
        for (int nf = 0; nf < 2; ++nf)
            acc[mf][nf] = (f32x4){0.f, 0.f, 0.f, 0.f};

    size_t xbase = (size_t)b * DV * NPP;
    const bf16x8* tFv = (const bf16x8*)tabFb;
    for (int s = 0; s < SPB; ++s) {
        int gs = ksb * SPB + s;
        int tb = gs * 32;
        bf16x8 a[4], bb[2];
        #pragma unroll
        for (int mf = 0; mf < 4; ++mf)
            a[mf] = *(const bf16x8*)&xhi[xbase + (size_t)(mf * 16 + r) * NPP + tb + g * 8];
        #pragma unroll
        for (int nf = 0; nf < 2; ++nf)
            bb[nf] = tFv[((size_t)gs * 8 + w * 2 + nf) * 64 + lane];
        #pragma unroll
        for (int mf = 0; mf < 4; ++mf)
            #pragma unroll
            for (int nf = 0; nf < 2; ++nf)
                acc[mf][nf] = __builtin_amdgcn_mfma_f32_16x16x32_bf16(a[mf], bb[nf], acc[mf][nf], 0, 0, 0);
    }
    // C layout: col = lane&15, row = (lane>>4)*4 + reg
    #pragma unroll
    for (int mf = 0; mf < 4; ++mf)
        #pragma unroll
        for (int nf = 0; nf < 2; ++nf)
            #pragma unroll
            for (int reg = 0; reg < 4; ++reg) {
                int c = mf * 16 + g * 4 + reg;
                int m = w * 32 + nf * 16 + r;
                xpart[(((size_t)ksb * NB + b) * DV + c) * 128 + m] = (__bf16)acc[mf][nf][reg];
            }
}

// ---------------- reduce partials + spectral mix -> zfrag (bf16, frag order) ----------------
__launch_bounds__(256)
__global__ void k_spec(const __bf16* __restrict__ xpart, const float* __restrict__ fw_l,
                       __bf16* __restrict__ zfrag) {
    __shared__ float Xs[DV][32];
    int b = blockIdx.y, kq = blockIdx.x, tid = threadIdx.x;
    #pragma unroll
    for (int q = 0; q < 8; ++q) {
        int flat = q * 256 + tid;
        int i = flat >> 5, mloc = flat & 31;
        float ssum = 0.f;
        #pragma unroll
        for (int ks = 0; ks < KSPL; ++ks)
            ssum += (float)xpart[(((size_t)ks * NB + b) * DV + i) * 128 + kq * 32 + mloc];
        Xs[i][mloc] = ssum;
    }
    __syncthreads();
    #pragma unroll
    for (int q = 0; q < 4; ++q) {
        int flat = q * 256 + tid;
        int o = flat >> 4, kl = flat & 15;
        int k = kq * 16 + kl;
        float yr = 0.f, yi = 0.f;
        #pragma unroll 8
        for (int i = 0; i < DV; ++i) {
            float2 xv = *(const float2*)&Xs[i][2 * kl];   // (cos-sum, sin-sum); true Xi = -sin-sum
            float2 wv = *(const float2*)&fw_l[(((size_t)i * DV + o) * NMODE + k) * 2];
            yr = fmaf(xv.x, wv.x, fmaf(xv.y, wv.y, yr));
            yi = fmaf(xv.x, wv.y, fmaf(-xv.y, wv.x, yi));
        }
        float al = (k == 0) ? (1.0f / NP) : (2.0f / NP);
        float z0 = al * yr, z1 = -al * yi;
        // zfrag: A[row=o][kdim=m]: ks=m>>5(=kq), mf=o>>4, lane=(o&15)+16*((m>>3)&3), j=m&7
        int mf = o >> 4, mm = 2 * kl;
        zfrag[((((size_t)b * 4 + kq) * 4 + mf) * 64 + (o & 15) + 16 * (mm >> 3)) * 8 + (mm & 7)] = (__bf16)z0;
        int mm1 = mm + 1;
        zfrag[((((size_t)b * 4 + kq) * 4 + mf) * 64 + (o & 15) + 16 * (mm1 >> 3)) * 8 + (mm1 & 7)] = (__bf16)z1;
    }
}

// ---------------- inverse DFT + bf16x3 local linear + bias (+relu | +q_w reduce) ----------------
// grid (65, NB); per block: 64 o x 128 t. K = 4 spectral steps + 6 local steps.
template <bool RELU, bool LAST>
__launch_bounds__(256)
__global__ void k_inv(const __bf16* __restrict__ zfrag, const __bf16* __restrict__ tabIb,
                      const __bf16* __restrict__ Wfrag_l, const float* __restrict__ wb_l,
                      const float* __restrict__ qw, const float* __restrict__ qb,
                      __bf16* __restrict__ xhi, __bf16* __restrict__ xlo,
                      float* __restrict__ out) {
    __shared__ __align__(16) __bf16 xb[2][2][8][64][8];  // [slab][ks][tf][lane][j] 32 KiB
    __shared__ float red[4][2][64];
    int b = blockIdx.y;
    int t0 = blockIdx.x * 128;
    int tid = threadIdx.x, w = tid >> 6, lane = tid & 63;
    int g = lane >> 4, cc = lane & 15;

    // ---- stage x_hi/x_lo tile (transposed into B-frag order) ----
    #pragma unroll
    for (int q = 0; q < 8; ++q) {
        int slot = q * 256 + tid;
        int ln = slot & 63;
        int tf = (slot >> 6) & 7;
        int ks = (slot >> 9) & 1;
        int slab = slot >> 10;
        const __bf16* src = slab ? xlo : xhi;
        int c0 = ks * 32 + (ln >> 4) * 8;
        int t = t0 + tf * 16 + (ln & 15);
        bf16x8 vv;
        #pragma unroll
        for (int j = 0; j < 8; ++j)
            vv[j] = src[((size_t)b * DV + c0 + j) * NPP + t];
        *(bf16x8*)&xb[slab][ks][tf][ln][0] = vv;
    }
    __syncthreads();

    f32x4 acc[4][2];
    #pragma unroll
    for (int mf = 0; mf < 4; ++mf)
        #pragma unroll
        for (int nf = 0; nf < 2; ++nf)
            acc[mf][nf] = (f32x4){0.f, 0.f, 0.f, 0.f};

    const bf16x8* zfv = (const bf16x8*)zfrag;
    const bf16x8* tIv = (const bf16x8*)tabIb;
    const bf16x8* wfv = (const bf16x8*)Wfrag_l;

    // ---- spectral: A = z, B = tabIb ----
    #pragma unroll
    for (int ks4 = 0; ks4 < 4; ++ks4) {
        bf16x8 a[4], bb[2];
        #pragma unroll
        for (int mf = 0; mf < 4; ++mf)
            a[mf] = zfv[(((size_t)b * 4 + ks4) * 4 + mf) * 64 + lane];
        #pragma unroll
        for (int nf = 0; nf < 2; ++nf)
            bb[nf] = tIv[((size_t)ks4 * TFRAGS + (t0 >> 4) + w * 2 + nf) * 64 + lane];
        #pragma unroll
        for (int mf = 0; mf < 4; ++mf)
            #pragma unroll
            for (int nf = 0; nf < 2; ++nf)
                acc[mf][nf] = __builtin_amdgcn_mfma_f32_16x16x32_bf16(a[mf], bb[nf], acc[mf][nf], 0, 0, 0);
    }
    // ---- local: Whi*xhi + Wlo*xhi + Whi*xlo ----
    #pragma unroll
    for (int trip = 0; trip < 3; ++trip) {
        int wslab = (trip == 1) ? 1 : 0;
        int xslab = (trip == 2) ? 1 : 0;
        #pragma unroll
        for (int ks = 0; ks < 2; ++ks) {
            bf16x8 a[4], bb[2];
            #pragma unroll
            for (int mf = 0; mf < 4; ++mf)
                a[mf] = wfv[((size_t)(wslab * 2 + ks) * 4 + mf) * 64 + lane];
            #pragma unroll
            for (int nf = 0; nf < 2; ++nf)
                bb[nf] = *(const bf16x8*)&xb[xslab][ks][w * 2 + nf][lane][0];
            #pragma unroll
            for (int mf = 0; mf < 4; ++mf)
                #pragma unroll
                for (int nf = 0; nf < 2; ++nf)
                    acc[mf][nf] = __builtin_amdgcn_mfma_f32_16x16x32_bf16(a[mf], bb[nf], acc[mf][nf], 0, 0, 0);
        }
    }

    if (!LAST) {
        #pragma unroll
        for (int mf = 0; mf < 4; ++mf)
            #pragma unroll
            for (int nf = 0; nf < 2; ++nf) {
                int t = t0 + w * 32 + nf * 16 + cc;
                #pragma unroll
                for (int reg = 0; reg < 4; ++reg) {
                    int o = mf * 16 + g * 4 + reg;
                    float val = acc[mf][nf][reg] + wb_l[o];
                    if (RELU) val = fmaxf(val, 0.f);
                    __bf16 h = (__bf16)val;
                    size_t ix = ((size_t)b * DV + o) * NPP + t;
                    xhi[ix] = h;
                    xlo[ix] = (__bf16)(val - (float)h);
                }
            }
    } else {
        float p0 = 0.f, p1 = 0.f;
        #pragma unroll
        for (int mf = 0; mf < 4; ++mf)
            #pragma unroll
            for (int reg = 0; reg < 4; ++reg) {
                int o = mf * 16 + g * 4 + reg;
                float qq = qw[o], bias = wb_l[o];
                p0 = fmaf(acc[mf][0][reg] + bias, qq, p0);
                p1 = fmaf(acc[mf][1][reg] + bias, qq, p1);
            }
        red[w][0][lane] = p0;
        red[w][1][lane] = p1;
        __syncthreads();
        if (tid < 128) {
            int w2 = tid >> 5, nf2 = (tid >> 4) & 1, c2 = tid & 15;
            float s = 0.f;
            #pragma unroll
            for (int g2 = 0; g2 < 4; ++g2) s += red[w2][nf2][g2 * 16 + c2];
            int t = t0 + w2 * 32 + nf2 * 16 + c2;
            if (t < NT) out[(size_t)b * NT + t] = s + qb[0];
        }
    }
}

extern "C" void kernel_launch(void* const* d_in, const int* in_sizes, int n_in,
                              void* d_out, int out_size, void* d_ws, size_t ws_size,
                              hipStream_t stream) {
    const float* v   = (const float*)d_in[0];
    const float* grd = (const float*)d_in[1];
    const float* pw  = (const float*)d_in[2];
    const float* pb  = (const float*)d_in[3];
    const float* fw  = (const float*)d_in[4];
    const float* ww  = (const float*)d_in[5];
    const float* wb  = (const float*)d_in[6];
    const float* qw  = (const float*)d_in[7];
    const float* qb  = (const float*)d_in[8];
    float* out = (float*)d_out;

    char* wsb = (char*)d_ws;
    __bf16* x_hi  = (__bf16*)(wsb + B_XHI);
    __bf16* x_lo  = (__bf16*)(wsb + B_XLO);
    __bf16* tabFb = (__bf16*)(wsb + B_TABF);
    __bf16* tabIb = (__bf16*)(wsb + B_TABI);
    __bf16* Wfrag = (__bf16*)(wsb + B_WFR);
    __bf16* zfrag = (__bf16*)(wsb + B_ZFR);
    __bf16* xpart = (__bf16*)(wsb + B_XPART);

    k_prep<<<(NPP * 64 + 255) / 256, 256, 0, stream>>>(tabFb, tabIb);
    k_prep_w<<<(NL * DV * DV + 255) / 256, 256, 0, stream>>>(ww, Wfrag);
    k_proj<<<dim3((NPP + 255) / 256, NB), 256, 0, stream>>>(v, grd, pw, pb, x_hi, x_lo);

    for (int l = 0; l < NL; ++l) {
        k_fdft<<<dim3(KSPL, NB), 256, 0, stream>>>(x_hi, tabFb, xpart);
        k_spec<<<dim3(4, NB), 256, 0, stream>>>(xpart, fw + (size_t)l * DV * DV * NMODE * 2, zfrag);
        const __bf16* wf_l = Wfrag + (size_t)l * 2 * 2 * 4 * 64 * 8;
        if (l < NL - 1) {
            k_inv<true, false><<<dim3(65, NB), 256, 0, stream>>>(
                zfrag, tabIb, wf_l, wb + (size_t)l * DV, qw, qb, x_hi, x_lo, out);
        } else {
            k_inv<false, true><<<dim3(65, NB), 256, 0, stream>>>(
                zfrag, tabIb, wf_l, wb + (size_t)l * DV, qw, qb, x_hi, x_lo, out);
        }
    }
}

// Round 4
// 495.791 us; speedup vs baseline: 3.8684x; 1.0991x over previous
//
#include <hip/hip_runtime.h>

#define NT    8192
#define NP    8200
#define NPP   8320          // 13 * 640 = 65 * 128
#define NB    64
#define DV    64
#define NL    4
#define KSB   13            // t-blocks for k_inv / fused DFT
#define TB    640           // t per k_inv block
#define NSUB  5             // subtiles of 128 t
#define PI2   6.28318530717958647692f

typedef _Float16 half8 __attribute__((ext_vector_type(8)));
typedef _Float16 half4 __attribute__((ext_vector_type(4)));
typedef float    f32x4 __attribute__((ext_vector_type(4)));

// ---------------- workspace layout (bytes) ----------------
static const size_t B_XT   = 0;
static const size_t B_TABF = 68157440ull;
static const size_t B_TABI = B_TABF + 2129920ull;
static const size_t B_WFR  = B_TABI + 2129920ull;
static const size_t B_ZFR  = B_WFR  + 131072ull;
static const size_t B_XP   = B_ZFR  + 1048576ull;
static const size_t B_VP   = B_XP   + 13631488ull;
static const size_t B_G    = B_VP   + 212992ull;

// ---------------- trig tables in MFMA fragment order ----------------
__global__ void k_prep(_Float16* __restrict__ tabF, _Float16* __restrict__ tabI) {
    int idx = blockIdx.x * 256 + threadIdx.x;
    if (idx >= NPP * 64) return;
    int t = idx >> 6, k = idx & 63;
    float c = 0.f, s = 0.f;
    if (t < NP) {
        int m = (int)(((long long)t * (long long)k) % NP);
        float th = (float)m * (PI2 / (float)NP);
        sincosf(th, &s, &c);
    }
    float al = (k == 0) ? (1.f / NP) : (2.f / NP);
    // tabF: B[k-dim=t][col=m]: frag step=t>>5, cf=m>>4, lane=(m&15)+16*((t>>3)&3), j=t&7
    {
        int gs = t >> 5, lh = (t >> 3) & 3, j = t & 7, cf = k >> 3;
        int m0 = 2 * k, m1 = 2 * k + 1;
        tabF[(((size_t)gs * 8 + cf) * 64 + (m0 & 15) + 16 * lh) * 8 + j] = (_Float16)c;
        tabF[(((size_t)gs * 8 + cf) * 64 + (m1 & 15) + 16 * lh) * 8 + j] = (_Float16)s;
    }
    // tabI: B[k-dim=m][col=t], alpha folded: ks=m>>5, tf=t>>4, lane=(t&15)+16*((m>>3)&3), j=m&7
    {
        int tf = t >> 4, lt = t & 15;
        int m0 = 2 * k, m1 = 2 * k + 1;
        tabI[(((size_t)(m0 >> 5) * 520 + tf) * 64 + lt + 16 * ((m0 >> 3) & 3)) * 8 + (m0 & 7)] = (_Float16)(al * c);
        tabI[(((size_t)(m1 >> 5) * 520 + tf) * 64 + lt + 16 * ((m1 >> 3) & 3)) * 8 + (m1 & 7)] = (_Float16)(al * s);
    }
}

// ---------------- w_w hi/lo f16 in A-frag order ----------------
__global__ void k_prep_w(const float* __restrict__ ww, _Float16* __restrict__ Wfrag) {
    int idx = blockIdx.x * 256 + threadIdx.x;
    if (idx >= NL * DV * DV) return;
    int l = idx >> 12, cd = idx & 4095, c = cd >> 6, d = cd & 63;
    float wv = ww[((size_t)l * DV + c) * DV + d];     // A[row=d][k=c]
    _Float16 h = (_Float16)wv;
    _Float16 lo = (_Float16)(wv - (float)h);
    int ks = c >> 5, mf = d >> 4;
    int lane = (d & 15) + 16 * ((c >> 3) & 3), j = c & 7;
    Wfrag[((((size_t)l * 2 + 0) * 2 + ks) * 4 + mf) * 512 + (size_t)lane * 8 + j] = h;
    Wfrag[((((size_t)l * 2 + 1) * 2 + ks) * 4 + mf) * 512 + (size_t)lane * 8 + j] = lo;
}

// ---------------- G[m] = DFT(grid) ----------------
__global__ void k_gd(const float* __restrict__ grd, float* __restrict__ G) {
    __shared__ float rb[256];
    int m = blockIdx.x, k = m >> 1, comp = m & 1;
    int tid = threadIdx.x;
    float s = 0.f;
    for (int t = tid; t < NT; t += 256) {
        int mm = (int)(((long long)t * (long long)k) % NP);
        float th = (float)mm * (PI2 / (float)NP);
        float sn, cs; sincosf(th, &sn, &cs);
        s += grd[t] * (comp ? sn : cs);
    }
    rb[tid] = s; __syncthreads();
    for (int h = 128; h > 0; h >>= 1) { if (tid < h) rb[tid] += rb[tid + h]; __syncthreads(); }
    if (tid == 0) G[m] = rb[0];
}

// ---------------- initial projection -> xT[b][t][c] f16 ----------------
__global__ void k_proj(const float* __restrict__ v, const float* __restrict__ grd,
                       const float* __restrict__ pw, const float* __restrict__ pb,
                       _Float16* __restrict__ xT) {
    int b = blockIdx.y;
    int t = blockIdx.x * 128 + (threadIdx.x >> 1);
    int hf = threadIdx.x & 1;
    bool in = (t < NT);
    float vv = in ? v[(size_t)b * NT + t] : 0.f;
    float gg = in ? grd[t] : 0.f;
    _Float16 buf[32];
    #pragma unroll
    for (int q = 0; q < 32; ++q) {
        int c = hf * 32 + q;
        float val = in ? fmaf(vv, pw[c], fmaf(gg, pw[64 + c], pb[c])) : 0.f;
        buf[q] = (_Float16)val;
    }
    #pragma unroll
    for (int q = 0; q < 4; ++q)
        *(half8*)&xT[((size_t)b * NPP + t) * 64 + hf * 32 + q * 8] = *(half8*)&buf[q * 8];
}

// ---------------- partial DFT of v (A rows = batch) ----------------
__launch_bounds__(256)
__global__ void k_fdft_v(const float* __restrict__ v, const _Float16* __restrict__ tabF,
                         _Float16* __restrict__ Vp) {
    int ksb = blockIdx.x;
    int tid = threadIdx.x, w = tid >> 6, lane = tid & 63, g = lane >> 4, r = lane & 15;
    const half8* tFv = (const half8*)tabF;
    f32x4 acc[4][2];
    #pragma unroll
    for (int mf = 0; mf < 4; ++mf)
        #pragma unroll
        for (int nf = 0; nf < 2; ++nf) acc[mf][nf] = (f32x4){0.f, 0.f, 0.f, 0.f};
    for (int s = 0; s < 20; ++s) {
        int gs = ksb * 20 + s;
        int t0 = gs * 32 + g * 8;
        half8 a[4];
        #pragma unroll
        for (int mf = 0; mf < 4; ++mf) {
            int brow = mf * 16 + r;
            half8 hv;
            if (t0 < NT) {
                const float4* pv = (const float4*)&v[(size_t)brow * NT + t0];
                float4 v0 = pv[0], v1 = pv[1];
                hv[0] = (_Float16)v0.x; hv[1] = (_Float16)v0.y; hv[2] = (_Float16)v0.z; hv[3] = (_Float16)v0.w;
                hv[4] = (_Float16)v1.x; hv[5] = (_Float16)v1.y; hv[6] = (_Float16)v1.z; hv[7] = (_Float16)v1.w;
            } else {
                #pragma unroll
                for (int j = 0; j < 8; ++j) hv[j] = (_Float16)0.f;
            }
            a[mf] = hv;
        }
        half8 bb[2];
        #pragma unroll
        for (int nf = 0; nf < 2; ++nf) bb[nf] = tFv[((size_t)gs * 8 + w * 2 + nf) * 64 + lane];
        #pragma unroll
        for (int mf = 0; mf < 4; ++mf)
            #pragma unroll
            for (int nf = 0; nf < 2; ++nf)
                acc[mf][nf] = __builtin_amdgcn_mfma_f32_16x16x32_f16(a[mf], bb[nf], acc[mf][nf], 0, 0, 0);
    }
    #pragma unroll
    for (int mf = 0; mf < 4; ++mf)
        #pragma unroll
        for (int nf = 0; nf < 2; ++nf)
            #pragma unroll
            for (int reg = 0; reg < 4; ++reg) {
                int brow = mf * 16 + g * 4 + reg;
                int m = w * 32 + nf * 16 + r;
                Vp[((size_t)ksb * NB + brow) * 128 + m] = (_Float16)acc[mf][nf][reg];
            }
}

// ---------------- spectral mix layer 0 (rank-2 X build) ----------------
__launch_bounds__(256)
__global__ void k_spec0(const _Float16* __restrict__ Vp, const float* __restrict__ G,
                        const float* __restrict__ pw, const float* __restrict__ pb,
                        const float* __restrict__ fw_l, _Float16* __restrict__ zfr) {
    __shared__ float Xs[64][32];
    __shared__ float Vs[32], Gs[32];
    int b = blockIdx.y, kq = blockIdx.x, tid = threadIdx.x;
    if (tid < 32) {
        int m = kq * 32 + tid;
        float ssum = 0.f;
        #pragma unroll
        for (int ks = 0; ks < KSB; ++ks) ssum += (float)Vp[((size_t)ks * NB + b) * 128 + m];
        Vs[tid] = ssum;
        Gs[tid] = G[m];
    }
    __syncthreads();
    #pragma unroll
    for (int q = 0; q < 8; ++q) {
        int flat = q * 256 + tid;
        int i = flat >> 5, ml = flat & 31;
        float xv = pw[i] * Vs[ml] + pw[64 + i] * Gs[ml];
        if (kq == 0 && ml == 0) xv += pb[i] * (float)NT;
        Xs[i][ml] = xv;
    }
    __syncthreads();
    #pragma unroll
    for (int q = 0; q < 4; ++q) {
        int flat = q * 256 + tid;
        int o = flat >> 4, kl = flat & 15;
        int k = kq * 16 + kl;
        float yr = 0.f, yi = 0.f;
        #pragma unroll 8
        for (int i = 0; i < 64; ++i) {
            float2 xv = *(const float2*)&Xs[i][2 * kl];
            float2 wv = *(const float2*)&fw_l[(((size_t)i * DV + o) * 64 + k) * 2];
            yr = fmaf(xv.x, wv.x, fmaf(xv.y, wv.y, yr));
            yi = fmaf(xv.x, wv.y, fmaf(-xv.y, wv.x, yi));
        }
        int mf = o >> 4, mm = 2 * kl, m1 = mm + 1;
        zfr[((((size_t)b * 4 + kq) * 4 + mf) * 64 + (o & 15) + 16 * (mm >> 3)) * 8 + (mm & 7)] = (_Float16)yr;
        zfr[((((size_t)b * 4 + kq) * 4 + mf) * 64 + (o & 15) + 16 * (m1 >> 3)) * 8 + (m1 & 7)] = (_Float16)(-yi);
    }
}

// ---------------- spectral mix layers 1..3 (reduce xpart) ----------------
__launch_bounds__(256)
__global__ void k_spec(const _Float16* __restrict__ xpart, const float* __restrict__ fw_l,
                       _Float16* __restrict__ zfr) {
    __shared__ float Xs[64][32];
    int b = blockIdx.y, kq = blockIdx.x, tid = threadIdx.x;
    #pragma unroll
    for (int q = 0; q < 8; ++q) {
        int flat = q * 256 + tid;
        int i = flat >> 5, ml = flat & 31;
        float ssum = 0.f;
        #pragma unroll
        for (int ks = 0; ks < KSB; ++ks)
            ssum += (float)xpart[(((size_t)ks * NB + b) * DV + i) * 128 + kq * 32 + ml];
        Xs[i][ml] = ssum;
    }
    __syncthreads();
    #pragma unroll
    for (int q = 0; q < 4; ++q) {
        int flat = q * 256 + tid;
        int o = flat >> 4, kl = flat & 15;
        int k = kq * 16 + kl;
        float yr = 0.f, yi = 0.f;
        #pragma unroll 8
        for (int i = 0; i < 64; ++i) {
            float2 xv = *(const float2*)&Xs[i][2 * kl];
            float2 wv = *(const float2*)&fw_l[(((size_t)i * DV + o) * 64 + k) * 2];
            yr = fmaf(xv.x, wv.x, fmaf(xv.y, wv.y, yr));
            yi = fmaf(xv.x, wv.y, fmaf(-xv.y, wv.x, yi));
        }
        int mf = o >> 4, mm = 2 * kl, m1 = mm + 1;
        zfr[((((size_t)b * 4 + kq) * 4 + mf) * 64 + (o & 15) + 16 * (mm >> 3)) * 8 + (mm & 7)] = (_Float16)yr;
        zfr[((((size_t)b * 4 + kq) * 4 + mf) * 64 + (o & 15) + 16 * (m1 >> 3)) * 8 + (m1 & 7)] = (_Float16)(-yi);
    }
}

// ---------------- fused: inverse DFT + local + bias + relu + fwd DFT of new x ----------------
template <bool LAST>
__launch_bounds__(256)
__global__ void k_inv(const _Float16* __restrict__ zfr, const _Float16* __restrict__ tabI,
                      const _Float16* __restrict__ tabF, const _Float16* __restrict__ Wl,
                      const float* __restrict__ wb_l, const float* __restrict__ qw,
                      const float* __restrict__ qb, _Float16* __restrict__ xT,
                      _Float16* __restrict__ xpart, float* __restrict__ out) {
    __shared__ _Float16 xls[64 * 128];    // [c][t-swizzled] 16 KiB
    __shared__ float red[4][2][64];
    int b = blockIdx.y, ksb = blockIdx.x;
    int tid = threadIdx.x, w = tid >> 6, lane = tid & 63;
    int g = lane >> 4, r = lane & 15;
    int tb0 = ksb * TB;
    const half8* zfv = (const half8*)zfr;
    const half8* tIv = (const half8*)tabI;
    const half8* tFv = (const half8*)tabF;
    const half8* wfv = (const half8*)Wl;

    f32x4 dacc[4][2];
    #pragma unroll
    for (int cf = 0; cf < 4; ++cf)
        #pragma unroll
        for (int nf = 0; nf < 2; ++nf) dacc[cf][nf] = (f32x4){0.f, 0.f, 0.f, 0.f};

    #pragma unroll 1
    for (int st = 0; st < NSUB; ++st) {
        int tw = tb0 + st * 128 + w * 32;
        // ---- old-x B-frags (direct coalesced global, this wave's own 32-t slice) ----
        half8 xb[2][2];
        #pragma unroll
        for (int ks = 0; ks < 2; ++ks)
            #pragma unroll
            for (int nf = 0; nf < 2; ++nf)
                xb[ks][nf] = *(const half8*)&xT[((size_t)b * NPP + tw + nf * 16 + r) * 64 + ks * 32 + g * 8];

        f32x4 acc[4][2];
        #pragma unroll
        for (int mf = 0; mf < 4; ++mf)
            #pragma unroll
            for (int nf = 0; nf < 2; ++nf) acc[mf][nf] = (f32x4){0.f, 0.f, 0.f, 0.f};

        // ---- spectral: A=z, B=tabI ----
        #pragma unroll
        for (int ks4 = 0; ks4 < 4; ++ks4) {
            half8 az[4], bt[2];
            #pragma unroll
            for (int mf = 0; mf < 4; ++mf)
                az[mf] = zfv[(((size_t)b * 4 + ks4) * 4 + mf) * 64 + lane];
            #pragma unroll
            for (int nf = 0; nf < 2; ++nf)
                bt[nf] = tIv[((size_t)ks4 * 520 + (tw >> 4) + nf) * 64 + lane];
            #pragma unroll
            for (int mf = 0; mf < 4; ++mf)
                #pragma unroll
                for (int nf = 0; nf < 2; ++nf)
                    acc[mf][nf] = __builtin_amdgcn_mfma_f32_16x16x32_f16(az[mf], bt[nf], acc[mf][nf], 0, 0, 0);
        }
        // ---- local: (Whi + Wlo) * x ----
        #pragma unroll
        for (int hl = 0; hl < 2; ++hl)
            #pragma unroll
            for (int ks = 0; ks < 2; ++ks) {
                half8 aw[4];
                #pragma unroll
                for (int mf = 0; mf < 4; ++mf)
                    aw[mf] = wfv[((size_t)(hl * 2 + ks) * 4 + mf) * 64 + lane];
                #pragma unroll
                for (int mf = 0; mf < 4; ++mf)
                    #pragma unroll
                    for (int nf = 0; nf < 2; ++nf)
                        acc[mf][nf] = __builtin_amdgcn_mfma_f32_16x16x32_f16(aw[mf], xb[ks][nf], acc[mf][nf], 0, 0, 0);
            }

        if (!LAST) {
            // ---- epilogue: bias + relu, store xT + LDS (swizzled [c][t]) ----
            #pragma unroll
            for (int mf = 0; mf < 4; ++mf)
                #pragma unroll
                for (int nf = 0; nf < 2; ++nf) {
                    int t = tw + nf * 16 + r;
                    int tl = w * 32 + nf * 16 + r;
                    half4 h4;
                    #pragma unroll
                    for (int reg = 0; reg < 4; ++reg) {
                        int o = mf * 16 + g * 4 + reg;
                        float val = fmaxf(acc[mf][nf][reg] + wb_l[o], 0.f);
                        h4[reg] = (_Float16)val;
                    }
                    *(half4*)&xT[((size_t)b * NPP + t) * 64 + mf * 16 + g * 4] = h4;
                    #pragma unroll
                    for (int reg = 0; reg < 4; ++reg) {
                        int c = mf * 16 + g * 4 + reg;
                        xls[(c << 7) + ((((tl << 1) ^ ((c & 15) << 4))) >> 1)] = h4[reg];
                    }
                }
            __syncthreads();
            // ---- fwd DFT of new x: A from LDS, B=tabF ----
            #pragma unroll
            for (int ks = 0; ks < 4; ++ks) {
                half8 ax[4], bf2[2];
                #pragma unroll
                for (int cf = 0; cf < 4; ++cf) {
                    int c = cf * 16 + r;
                    int off = (ks * 64 + g * 16) ^ ((c & 15) << 4);
                    ax[cf] = *(const half8*)&xls[(c << 7) + (off >> 1)];
                }
                int gs = ksb * 20 + st * 4 + ks;
                #pragma unroll
                for (int nf2 = 0; nf2 < 2; ++nf2)
                    bf2[nf2] = tFv[((size_t)gs * 8 + w * 2 + nf2) * 64 + lane];
                #pragma unroll
                for (int cf = 0; cf < 4; ++cf)
                    #pragma unroll
                    for (int nf2 = 0; nf2 < 2; ++nf2)
                        dacc[cf][nf2] = __builtin_amdgcn_mfma_f32_16x16x32_f16(ax[cf], bf2[nf2], dacc[cf][nf2], 0, 0, 0);
            }
            __syncthreads();
        } else {
            float p0 = 0.f, p1 = 0.f;
            #pragma unroll
            for (int mf = 0; mf < 4; ++mf)
                #pragma unroll
                for (int reg = 0; reg < 4; ++reg) {
                    int o = mf * 16 + g * 4 + reg;
                    float qq = qw[o], bias = wb_l[o];
                    p0 = fmaf(acc[mf][0][reg] + bias, qq, p0);
                    p1 = fmaf(acc[mf][1][reg] + bias, qq, p1);
                }
            red[w][0][lane] = p0;
            red[w][1][lane] = p1;
            __syncthreads();
            if (tid < 128) {
                int w2 = tid >> 5, nf2 = (tid >> 4) & 1, c2 = tid & 15;
                float s2 = 0.f;
                #pragma unroll
                for (int g2 = 0; g2 < 4; ++g2) s2 += red[w2][nf2][g2 * 16 + c2];
                int t = tb0 + st * 128 + w2 * 32 + nf2 * 16 + c2;
                if (t < NT) out[(size_t)b * NT + t] = s2 + qb[0];
            }
            __syncthreads();
        }
    }
    if (!LAST) {
        #pragma unroll
        for (int cf = 0; cf < 4; ++cf)
            #pragma unroll
            for (int nf2 = 0; nf2 < 2; ++nf2)
                #pragma unroll
                for (int reg = 0; reg < 4; ++reg) {
                    int c = cf * 16 + g * 4 + reg;
                    int m = w * 32 + nf2 * 16 + r;
                    xpart[(((size_t)ksb * NB + b) * DV + c) * 128 + m] = (_Float16)dacc[cf][nf2][reg];
                }
    }
}

extern "C" void kernel_launch(void* const* d_in, const int* in_sizes, int n_in,
                              void* d_out, int out_size, void* d_ws, size_t ws_size,
                              hipStream_t stream) {
    const float* v   = (const float*)d_in[0];
    const float* grd = (const float*)d_in[1];
    const float* pw  = (const float*)d_in[2];
    const float* pb  = (const float*)d_in[3];
    const float* fw  = (const float*)d_in[4];
    const float* ww  = (const float*)d_in[5];
    const float* wb  = (const float*)d_in[6];
    const float* qw  = (const float*)d_in[7];
    const float* qb  = (const float*)d_in[8];
    float* out = (float*)d_out;

    char* wsb = (char*)d_ws;
    _Float16* xT    = (_Float16*)(wsb + B_XT);
    _Float16* tabFb = (_Float16*)(wsb + B_TABF);
    _Float16* tabIb = (_Float16*)(wsb + B_TABI);
    _Float16* Wfrag = (_Float16*)(wsb + B_WFR);
    _Float16* zfrag = (_Float16*)(wsb + B_ZFR);
    _Float16* xpart = (_Float16*)(wsb + B_XP);
    _Float16* Vpart = (_Float16*)(wsb + B_VP);
    float*    G     = (float*)(wsb + B_G);

    k_prep<<<(NPP * 64 + 255) / 256, 256, 0, stream>>>(tabFb, tabIb);
    k_prep_w<<<(NL * DV * DV + 255) / 256, 256, 0, stream>>>(ww, Wfrag);
    k_gd<<<128, 256, 0, stream>>>(grd, G);
    k_proj<<<dim3(65, NB), 256, 0, stream>>>(v, grd, pw, pb, xT);
    k_fdft_v<<<KSB, 256, 0, stream>>>(v, tabFb, Vpart);

    for (int l = 0; l < NL; ++l) {
        if (l == 0)
            k_spec0<<<dim3(4, NB), 256, 0, stream>>>(Vpart, G, pw, pb, fw, zfrag);
        else
            k_spec<<<dim3(4, NB), 256, 0, stream>>>(xpart, fw + (size_t)l * DV * DV * 64 * 2, zfrag);
        // per-layer Wfrag block = 2(hilo) * 2(ks) * 4(mf) * 64(lane) * 8(j) = 8192 f16
        const _Float16* wf_l = Wfrag + (size_t)l * 8192;
        const float* wb_l = wb + (size_t)l * DV;
        if (l < NL - 1)
            k_inv<false><<<dim3(KSB, NB), 256, 0, stream>>>(
                zfrag, tabIb, tabFb, wf_l, wb_l, qw, qb, xT, xpart, out);
        else
            k_inv<true><<<dim3(KSB, NB), 256, 0, stream>>>(
                zfrag, tabIb, tabFb, wf_l, wb_l, qw, qb, xT, xpart, out);
    }
}